// Round 3
// baseline (2321.808 us; speedup 1.0000x reference)
//
#include <hip/hip_runtime.h>
#include <math.h>

#define B_ 64
#define T_ 48
#define H_ 512
#define V_ 32000
#define G_ 2048
#define BH_ (B_*H_)
#define BG_ (B_*G_)

typedef short short8 __attribute__((ext_vector_type(8)));
typedef float f32x4 __attribute__((ext_vector_type(4)));

__device__ __forceinline__ float sigmoidf_(float x){ return 1.f/(1.f+__expf(-x)); }

__device__ __forceinline__ unsigned short f2bf(float f){
  unsigned u = __float_as_uint(f);
  u += 0x7fffu + ((u>>16)&1u);
  return (unsigned short)(u>>16);
}

__device__ __forceinline__ short8 cvt8(const float* g){
  float4 a = *(const float4*)g;
  float4 b = *(const float4*)(g+4);
  short8 v;
  v[0]=(short)f2bf(a.x); v[1]=(short)f2bf(a.y); v[2]=(short)f2bf(a.z); v[3]=(short)f2bf(a.w);
  v[4]=(short)f2bf(b.x); v[5]=(short)f2bf(b.y); v[6]=(short)f2bf(b.z); v[7]=(short)f2bf(b.w);
  return v;
}

// ---------------------------------------------------------------------------
// init: zero h1[0], h2[0] (bf16) and the grid-barrier flags
// ---------------------------------------------------------------------------
__global__ void init_kernel(unsigned short* h1_0, unsigned short* h2_0, unsigned* flags){
  int i = blockIdx.x*256 + threadIdx.x;   // 32 blocks -> 8192 threads
  short8 z = {0,0,0,0,0,0,0,0};
  if (i < 4096) ((short8*)h1_0)[i] = z;
  else          ((short8*)h2_0)[i-4096] = z;
  if (i < 128) flags[i] = 0u;
}

// ---------------------------------------------------------------------------
// cvt_cat: dst[r][0..511] = bf16(s0[r*ld0+off0+k]); dst[r][512..dld) from s1
// ---------------------------------------------------------------------------
__global__ void cvt_cat_kernel(const float* __restrict__ s0, int ld0, int off0,
                               const float* __restrict__ s1, int ld1, int off1,
                               unsigned short* __restrict__ dst, int dld, long total8)
{
  int cols8 = dld >> 3;
  for (long i = blockIdx.x*256 + threadIdx.x; i < total8; i += (long)gridDim.x*256){
    int r = (int)(i / cols8);
    int k = (int)(i - (long)r*cols8) * 8;
    short8 v = (k < 512 || !s1) ? cvt8(s0 + (long)r*ld0 + off0 + k)
                                : cvt8(s1 + (long)r*ld1 + off1 + (k-512));
    *(short8*)(dst + (long)r*dld + k) = v;
  }
}

__global__ void bias_sum_kernel(const float* a1, const float* a2, float* o1,
                                const float* b1, const float* b2, float* o2){
  int n = blockIdx.x*256 + threadIdx.x;
  if (n < G_){ o1[n] = a1[n] + a2[n]; o2[n] = b1[n] + b2[n]; }
}

// ---------------------------------------------------------------------------
// mm_pre: out[s] = A_slice(s) @ W[:, koff:koff+512].T + bA + bB
// A_slice(s): row b at A + b*a_bstride + s*H_.  M=64, N=2048 (8 tiles), K=512.
// grid (S, 8), 512 threads = 8 waves.
// ---------------------------------------------------------------------------
__global__ __launch_bounds__(512,1) void mm_pre_kernel(
    const float* __restrict__ A, int a_bstride,
    const float* __restrict__ W, int ld, int koff,
    const float* __restrict__ bA, const float* __restrict__ bB,
    float* __restrict__ out)
{
  const int s = blockIdx.x, n0 = blockIdx.y*256;
  const int t = threadIdx.x, w = t>>6, l = t&63, ln = l&15, lk = l>>4;
  __shared__ short8 smA[64*64];
  __shared__ short8 smB[256*8];

  const float* af32 = A + (long)s*H_;

  f32x4 acc[4][2];
#pragma unroll
  for (int mf=0; mf<4; ++mf)
#pragma unroll
    for (int nf=0; nf<2; ++nf) acc[mf][nf] = (f32x4){0.f,0.f,0.f,0.f};

#pragma unroll
  for (int i=0;i<8;++i){ int e=i*4096+t*8; int m=e>>9, k=e&511;
    smA[m*64 + ((k>>3)^(m&7))] = cvt8(&af32[(long)m*a_bstride + k]); }

  for (int kc=0; kc<8; ++kc){
    __syncthreads();
#pragma unroll
    for (int i=0;i<4;++i){ int e=i*4096+t*8; int n=e>>6, k=e&63;
      smB[n*8 + ((k>>3)^(n&7))] = cvt8(&W[(long)(n0+n)*ld + koff + kc*64 + k]); }
    __syncthreads();
#pragma unroll
    for (int ks2=0; ks2<2; ++ks2){
#pragma unroll
      for (int nf=0; nf<2; ++nf){
        int n = w*32 + nf*16 + ln;
        short8 bfr = smB[n*8 + ((ks2*4+lk)^(n&7))];
#pragma unroll
        for (int mf=0; mf<4; ++mf){
          int m = mf*16+ln;
          short8 afr = smA[m*64 + (((kc*2+ks2)*4+lk)^(m&7))];
          acc[mf][nf] = __builtin_amdgcn_mfma_f32_16x16x32_bf16(afr, bfr, acc[mf][nf], 0,0,0);
        }
      }
    }
  }
#pragma unroll
  for (int nf=0; nf<2; ++nf){
    int n = n0 + w*32 + nf*16 + ln;
    float bias = bA[n] + bB[n];
#pragma unroll
    for (int mf=0; mf<4; ++mf)
#pragma unroll
      for (int r=0; r<4; ++r){
        int m = mf*16 + lk*4 + r;
        out[(long)s*BG_ + (long)m*G_ + n] = acc[mf][nf][r] + bias;
      }
  }
}

// ---------------------------------------------------------------------------
// fused_chain: 64 persistent blocks. Blocks 0..31 = layer-1, 32..63 = layer-2
// (lagging one step, K=1024 concat [h2|h1] vs cat-weights [w_hh|w_ih-h1part]).
// Weights resident in VGPRs (bf16). c-state in LDS. All-to-all flag barrier.
// ---------------------------------------------------------------------------
__global__ __launch_bounds__(256,1) void fused_chain_kernel(
    const unsigned short* __restrict__ w1e, const unsigned short* __restrict__ w1d, // [2048][512]
    const unsigned short* __restrict__ w2e, const unsigned short* __restrict__ w2d, // [2048][1024]
    const float* __restrict__ x1,   // [48][64][2048] feat@w_ih1^T + b_ih1+b_hh1
    const float* __restrict__ capq, // [47][64][2048] cap@w_ihd2[:,:512]^T + b_ihd2+b_hhd2
    const float* __restrict__ bd1s, // [2048] b_ihd1+b_hhd1
    const float* __restrict__ b2es, // [2048] b_ih2+b_hh2
    unsigned short* __restrict__ h1, unsigned short* __restrict__ h2, // [96][64][512]
    unsigned* __restrict__ flags)
{
  const int bc = blockIdx.x;
  const int isL2 = (bc >= 32);
  const int cb = bc & 31;
  const int t = threadIdx.x;
  const int wv = t>>6, l = t&63, ln = l&15, lk = l>>4;

  __shared__ short8 smA[64*128];        // 128 KB: [m][K=1024] bf16, XOR-swizzled
  __shared__ float gbuf[4][16][68];     // 17 KB
  __shared__ float c_lds[16][68];       // 4.3 KB
  unsigned short* stash = (unsigned short*)&smA[0];  // aliased (smA dead at cell-update)

  short8 We[32], Wd[32];
  const int col = wv*512 + cb*16 + ln;  // gate-row this lane owns
  if (isL2){
    const long wrow = (long)col * 1024;
#pragma unroll
    for (int ks=0; ks<32; ++ks){
      We[ks] = *(const short8*)(w2e + wrow + ks*32 + lk*8);
      Wd[ks] = *(const short8*)(w2d + wrow + ks*32 + lk*8);
    }
  } else {
    const long wrow = (long)col * 512;
#pragma unroll
    for (int ks=0; ks<16; ++ks){
      We[ks] = *(const short8*)(w1e + wrow + ks*32 + lk*8);
      Wd[ks] = *(const short8*)(w1d + wrow + ks*32 + lk*8);
    }
  }
  const float bext = isL2 ? b2es[col] : bd1s[col];

  for (int i=t; i<16*68; i+=256) (&c_lds[0][0])[i] = 0.f;

  for (int s=0; s<96; ++s){
    const int active = isL2 ? (s>=1) : (s<95);
    if (active){
      // ---- stage A ----
      if (!isL2){
        const unsigned short* hp = h1 + (long)s*BH_;
#pragma unroll
        for (int i=0;i<16;++i){ int e=i*2048+t*8; int m=e>>9, k=e&511;
          smA[m*128 + ((k>>3)^(m&7))] = *(const short8*)(hp + m*512 + k); }
      } else {
        const unsigned short* hpA = h2 + (long)(s-1)*BH_;
        const unsigned short* hpB = h1 + (long)s*BH_;
#pragma unroll
        for (int i=0;i<16;++i){ int e=i*2048+t*8; int m=e>>9, k=e&511;
          smA[m*128 + ((k>>3)^(m&7))]      = *(const short8*)(hpA + m*512 + k);
          smA[m*128 + ((k>>3)^(m&7)) + 64] = *(const short8*)(hpB + m*512 + k);
        }
      }
      __syncthreads();

      const int dec = isL2 ? ((s-1)>=48) : (s>=48);
      f32x4 acc[4];
#pragma unroll
      for (int mf=0;mf<4;++mf) acc[mf] = (f32x4){0.f,0.f,0.f,0.f};

      if (isL2){
        if (!dec){
#pragma unroll
          for (int ks=0; ks<32; ++ks)
#pragma unroll
            for (int mf=0; mf<4; ++mf){
              int m = mf*16+ln;
              acc[mf] = __builtin_amdgcn_mfma_f32_16x16x32_bf16(
                smA[m*128 + ((ks*4+lk)^(m&7))], We[ks], acc[mf], 0,0,0);
            }
        } else {
#pragma unroll
          for (int ks=0; ks<32; ++ks)
#pragma unroll
            for (int mf=0; mf<4; ++mf){
              int m = mf*16+ln;
              acc[mf] = __builtin_amdgcn_mfma_f32_16x16x32_bf16(
                smA[m*128 + ((ks*4+lk)^(m&7))], Wd[ks], acc[mf], 0,0,0);
            }
        }
      } else {
        if (!dec){
#pragma unroll
          for (int ks=0; ks<16; ++ks)
#pragma unroll
            for (int mf=0; mf<4; ++mf){
              int m = mf*16+ln;
              acc[mf] = __builtin_amdgcn_mfma_f32_16x16x32_bf16(
                smA[m*128 + ((ks*4+lk)^(m&7))], We[ks], acc[mf], 0,0,0);
            }
        } else {
#pragma unroll
          for (int ks=0; ks<16; ++ks)
#pragma unroll
            for (int mf=0; mf<4; ++mf){
              int m = mf*16+ln;
              acc[mf] = __builtin_amdgcn_mfma_f32_16x16x32_bf16(
                smA[m*128 + ((ks*4+lk)^(m&7))], Wd[ks], acc[mf], 0,0,0);
            }
        }
      }

      // ---- pre / bias ----
      if (!isL2){
        if (s < 48){
          const float* pp = x1 + (long)s*BG_ + col;
#pragma unroll
          for (int mf=0;mf<4;++mf)
#pragma unroll
            for (int r=0;r<4;++r) acc[mf][r] += pp[(long)(mf*16+lk*4+r)*G_];
        } else {
#pragma unroll
          for (int mf=0;mf<4;++mf)
#pragma unroll
            for (int r=0;r<4;++r) acc[mf][r] += bext;
        }
      } else {
        int s2 = s-1;
        if (s2 < 48){
#pragma unroll
          for (int mf=0;mf<4;++mf)
#pragma unroll
            for (int r=0;r<4;++r) acc[mf][r] += bext;
        } else {
          const float* pp = capq + (long)(s2-48)*BG_ + col;
#pragma unroll
          for (int mf=0;mf<4;++mf)
#pragma unroll
            for (int r=0;r<4;++r) acc[mf][r] += pp[(long)(mf*16+lk*4+r)*G_];
        }
      }

#pragma unroll
      for (int mf=0;mf<4;++mf) *(f32x4*)&gbuf[wv][ln][mf*16+lk*4] = acc[mf];
      __syncthreads();   // gbuf ready; also: all smA MFMA reads done -> stash alias safe

      {
        int n = t&15, m0 = (t>>4)*4;
        float4 gi = *(float4*)&gbuf[0][n][m0];
        float4 gf = *(float4*)&gbuf[1][n][m0];
        float4 gg = *(float4*)&gbuf[2][n][m0];
        float4 go = *(float4*)&gbuf[3][n][m0];
        float4 c4 = *(float4*)&c_lds[n][m0];
        float a_i[4]={gi.x,gi.y,gi.z,gi.w}, a_f[4]={gf.x,gf.y,gf.z,gf.w};
        float a_g[4]={gg.x,gg.y,gg.z,gg.w}, a_o[4]={go.x,go.y,go.z,go.w};
        float ci[4]={c4.x,c4.y,c4.z,c4.w};
        float cn[4];
#pragma unroll
        for (int j=0;j<4;++j){
          float i_ = sigmoidf_(a_i[j]), f_ = sigmoidf_(a_f[j]), o_ = sigmoidf_(a_o[j]);
          float g_ = tanhf(a_g[j]);
          cn[j] = f_*ci[j] + i_*g_;
          stash[(m0+j)*24 + n] = f2bf(o_*tanhf(cn[j]));
        }
        *(float4*)&c_lds[n][m0] = make_float4(cn[0],cn[1],cn[2],cn[3]);
      }
      __syncthreads();

      {
        unsigned short* ho = (isL2 ? (h2 + (long)s*BH_) : (h1 + (long)(s+1)*BH_)) + cb*16;
        if (t < 128){
          int m = t>>1, part = t&1;
          *(short8*)(ho + (long)m*512 + part*8) = *(const short8*)&stash[m*24 + part*8];
        }
      }
    }

    // ---- all-to-all grid barrier (64 blocks) ----
    if (s < 95){
      unsigned gen = (unsigned)(s+1);
      __threadfence();
      __syncthreads();
      if (t < 64){
        if (t == 0)
          __hip_atomic_store(&flags[bc], gen, __ATOMIC_RELEASE, __HIP_MEMORY_SCOPE_AGENT);
        while (__hip_atomic_load(&flags[t], __ATOMIC_ACQUIRE, __HIP_MEMORY_SCOPE_AGENT) < gen){}
        __threadfence();
      }
      __syncthreads();
    }
  }
}

// ---------------------------------------------------------------------------
// CE: logits (bf16 MFMA) + sum-exp partials + target-logit gather
// grid (td 47, vt 125), 512 threads, M=64 N=256 K=512
// ---------------------------------------------------------------------------
__global__ __launch_bounds__(512,1) void ce_mfma_kernel(
    const unsigned short* __restrict__ h2_bf, const float* __restrict__ w_o,
    const float* __restrict__ b_o, const int* __restrict__ ids,
    float* __restrict__ partial, float* __restrict__ tgt)
{
  const int td = blockIdx.x, vt = blockIdx.y, v0 = vt*256;
  const int t = threadIdx.x, w = t>>6, l = t&63, ln = l&15, lk = l>>4;
  __shared__ short8 smA[64*64];
  __shared__ short8 smB[256*8];
  __shared__ float red[8][64];
  __shared__ int tid_s[64];

  const unsigned short* hp = h2_bf + (long)(49+td)*BH_;
  if (t < 64) tid_s[t] = ids[t*T_ + td + 1];
#pragma unroll
  for (int i=0;i<8;++i){ int e=i*4096+t*8; int m=e>>9, k=e&511;
    smA[m*64 + ((k>>3)^(m&7))] = *(const short8*)(hp + m*512 + k); }

  f32x4 acc[4][2];
#pragma unroll
  for (int mf=0; mf<4; ++mf)
#pragma unroll
    for (int nf=0; nf<2; ++nf) acc[mf][nf] = (f32x4){0.f,0.f,0.f,0.f};

  for (int kc=0; kc<8; ++kc){
    __syncthreads();
#pragma unroll
    for (int i=0;i<4;++i){ int e=i*4096+t*8; int n=e>>6, k=e&63;
      smB[n*8 + ((k>>3)^(n&7))] = cvt8(&w_o[(long)(v0+n)*512 + kc*64 + k]); }
    __syncthreads();
#pragma unroll
    for (int ks2=0; ks2<2; ++ks2){
#pragma unroll
      for (int nf=0; nf<2; ++nf){
        int n = w*32 + nf*16 + ln;
        short8 bfr = smB[n*8 + ((ks2*4+lk)^(n&7))];
#pragma unroll
        for (int mf=0; mf<4; ++mf){
          int m = mf*16+ln;
          short8 afr = smA[m*64 + (((kc*2+ks2)*4+lk)^(m&7))];
          acc[mf][nf] = __builtin_amdgcn_mfma_f32_16x16x32_bf16(afr, bfr, acc[mf][nf], 0,0,0);
        }
      }
    }
  }

  float se[4][4];
#pragma unroll
  for (int mf=0; mf<4; ++mf)
#pragma unroll
    for (int r=0;r<4;++r) se[mf][r] = 0.f;
#pragma unroll
  for (int nf=0; nf<2; ++nf){
    int ng = v0 + w*32 + nf*16 + ln;
    float bo = b_o[ng];
#pragma unroll
    for (int mf=0; mf<4; ++mf)
#pragma unroll
      for (int r=0;r<4;++r){
        int m = mf*16 + lk*4 + r;
        float lg = acc[mf][nf][r] + bo;
        se[mf][r] += __expf(lg);
        if (ng == tid_s[m]) tgt[td*64 + m] = lg;
      }
  }
#pragma unroll
  for (int off=1; off<16; off<<=1)
#pragma unroll
    for (int mf=0; mf<4; ++mf)
#pragma unroll
      for (int r=0;r<4;++r) se[mf][r] += __shfl_xor(se[mf][r], off);
  if (ln == 0){
#pragma unroll
    for (int mf=0; mf<4; ++mf)
      *(f32x4*)&red[w][mf*16 + lk*4] = (f32x4){se[mf][0],se[mf][1],se[mf][2],se[mf][3]};
  }
  __syncthreads();
  if (t < 64){
    float ssum = 0.f;
#pragma unroll
    for (int w2=0; w2<8; ++w2) ssum += red[w2][t];
    partial[(long)vt*3008 + td*64 + t] = ssum;
  }
}

__global__ void ce_combine(const float* __restrict__ partial, const float* __restrict__ tgt,
                           float* __restrict__ ce_row){
  int r = blockIdx.x*256 + threadIdx.x;
  if (r < 3008){
    float s = 0.f;
    for (int i=0;i<125;++i) s += partial[(long)i*3008 + r];
    ce_row[r] = __logf(s) - tgt[r];
  }
}

__global__ void ce_final(const float* __restrict__ ce_row, float* __restrict__ out){
  __shared__ float red[256];
  float s = 0.f;
  for (int i=threadIdx.x; i<3008; i+=256) s += ce_row[i];
  red[threadIdx.x] = s;
  __syncthreads();
  for (int off=128; off>0; off>>=1){
    if (threadIdx.x < off) red[threadIdx.x] += red[threadIdx.x + off];
    __syncthreads();
  }
  if (threadIdx.x == 0) out[0] = red[0] * (1.0f/4096.0f);
}

// ---------------------------------------------------------------------------
extern "C" void kernel_launch(void* const* d_in, const int* in_sizes, int n_in,
                              void* d_out, int out_size, void* d_ws, size_t ws_size,
                              hipStream_t stream)
{
  (void)in_sizes; (void)n_in; (void)out_size; (void)ws_size;
  const float* feat    = (const float*)d_in[0];
  const float* caption = (const float*)d_in[1];
  const int*   ids     = (const int*)d_in[2];
  const float* w_ih1  = (const float*)d_in[3];
  const float* w_hh1  = (const float*)d_in[4];
  const float* b_ih1  = (const float*)d_in[5];
  const float* b_hh1  = (const float*)d_in[6];
  const float* w_ih2  = (const float*)d_in[7];
  const float* w_hh2  = (const float*)d_in[8];
  const float* b_ih2  = (const float*)d_in[9];
  const float* b_hh2  = (const float*)d_in[10];
  const float* w_hhd1 = (const float*)d_in[12];
  const float* b_ihd1 = (const float*)d_in[13];
  const float* b_hhd1 = (const float*)d_in[14];
  const float* w_ihd2 = (const float*)d_in[15];
  const float* w_hhd2 = (const float*)d_in[16];
  const float* b_ihd2 = (const float*)d_in[17];
  const float* b_hhd2 = (const float*)d_in[18];
  const float* w_o    = (const float*)d_in[19];
  const float* b_o    = (const float*)d_in[20];

  char* p = (char*)d_ws;
  unsigned short* h1   = (unsigned short*)p; p += 96L*BH_*2;       // 6.29 MB
  unsigned short* h2   = (unsigned short*)p; p += 96L*BH_*2;       // 6.29 MB
  unsigned short* w1e  = (unsigned short*)p; p += 2048L*512*2;     // 2.10 MB
  unsigned short* w1d  = (unsigned short*)p; p += 2048L*512*2;
  unsigned short* w2e  = (unsigned short*)p; p += 2048L*1024*2;    // 4.19 MB
  unsigned short* w2d  = (unsigned short*)p; p += 2048L*1024*2;
  float* x1    = (float*)p; p += 48L*BG_*4;                        // 25.2 MB
  float* capq  = (float*)p; p += 47L*BG_*4;                        // 24.6 MB
  float* bd1s  = (float*)p; p += 2048*4;
  float* b2es  = (float*)p; p += 2048*4;
  float* partial = (float*)p; p += 125L*3008*4;                    // 1.50 MB
  float* tgt   = (float*)p; p += 3008*4;
  float* ce_row= (float*)p; p += 3008*4;
  unsigned* flags = (unsigned*)p; p += 128*4;

  init_kernel<<<32, 256, 0, stream>>>(h1, h2, flags);

  // weight conversions to bf16 (cat layout for layer-2)
  cvt_cat_kernel<<<512, 256, 0, stream>>>(w_hh1, 512, 0, nullptr, 0, 0, w1e, 512, 2048L*64);
  cvt_cat_kernel<<<512, 256, 0, stream>>>(w_hhd1, 512, 0, nullptr, 0, 0, w1d, 512, 2048L*64);
  cvt_cat_kernel<<<512, 256, 0, stream>>>(w_hh2, 512, 0, w_ih2, 1024, 512, w2e, 1024, 2048L*128);
  cvt_cat_kernel<<<512, 256, 0, stream>>>(w_hhd2, 512, 0, w_ihd2, 1024, 512, w2d, 1024, 2048L*128);
  bias_sum_kernel<<<8, 256, 0, stream>>>(b_ihd1, b_hhd1, bd1s, b_ih2, b_hh2, b2es);

  // X1[s] = feat_s @ w_ih1^T + b_ih1 + b_hh1           (48 slots)
  mm_pre_kernel<<<dim3(48,8), 512, 0, stream>>>(feat, T_*H_, w_ih1, 512, 0, b_ih1, b_hh1, x1);
  // capQ[j] = cap_j @ w_ihd2[:,:512]^T + b_ihd2+b_hhd2 (47 slots)
  mm_pre_kernel<<<dim3(47,8), 512, 0, stream>>>(caption, T_*H_, w_ihd2, 1024, 0, b_ihd2, b_hhd2, capq);

  // fused two-layer chain, 95 grid barriers
  fused_chain_kernel<<<64, 256, 0, stream>>>(w1e, w1d, w2e, w2d, x1, capq, bd1s, b2es, h1, h2, flags);

  // CE
  ce_mfma_kernel<<<dim3(47,125), 512, 0, stream>>>(h2, w_o, b_o, ids, partial, tgt);
  ce_combine<<<12, 256, 0, stream>>>(partial, tgt, ce_row);
  ce_final<<<1, 256, 0, stream>>>(ce_row, (float*)d_out);
}

// Round 4
// 1902.570 us; speedup vs baseline: 1.2204x; 1.2204x over previous
//
#include <hip/hip_runtime.h>
#include <math.h>

#define B_ 64
#define T_ 48
#define H_ 512
#define V_ 32000
#define G_ 2048
#define BH_ (B_*H_)
#define BG_ (B_*G_)

typedef short short8 __attribute__((ext_vector_type(8)));
typedef float f32x4 __attribute__((ext_vector_type(4)));

__device__ __forceinline__ float sigmoidf_(float x){ return 1.f/(1.f+__expf(-x)); }

__device__ __forceinline__ unsigned short f2bf(float f){
  unsigned u = __float_as_uint(f);
  u += 0x7fffu + ((u>>16)&1u);
  return (unsigned short)(u>>16);
}

__device__ __forceinline__ short8 cvt8(const float* g){
  float4 a = *(const float4*)g;
  float4 b = *(const float4*)(g+4);
  short8 v;
  v[0]=(short)f2bf(a.x); v[1]=(short)f2bf(a.y); v[2]=(short)f2bf(a.z); v[3]=(short)f2bf(a.w);
  v[4]=(short)f2bf(b.x); v[5]=(short)f2bf(b.y); v[6]=(short)f2bf(b.z); v[7]=(short)f2bf(b.w);
  return v;
}

// ---------------------------------------------------------------------------
// init: zero h1[0], h2[0] (bf16) and the grid-barrier flags/gen
// ---------------------------------------------------------------------------
__global__ void init_kernel(unsigned short* h1_0, unsigned short* h2_0, unsigned* flags){
  int i = blockIdx.x*256 + threadIdx.x;   // 32 blocks -> 8192 threads
  short8 z = {0,0,0,0,0,0,0,0};
  if (i < 4096) ((short8*)h1_0)[i] = z;
  else          ((short8*)h2_0)[i-4096] = z;
  if (i < 1152) flags[i] = 0u;            // 64 padded flags + gen line
}

// ---------------------------------------------------------------------------
// cvt_cat: dst[r][0..511] = bf16(s0[r*ld0+off0+k]); dst[r][512..dld) from s1
// ---------------------------------------------------------------------------
__global__ void cvt_cat_kernel(const float* __restrict__ s0, int ld0, int off0,
                               const float* __restrict__ s1, int ld1, int off1,
                               unsigned short* __restrict__ dst, int dld, long total8)
{
  int cols8 = dld >> 3;
  for (long i = blockIdx.x*256 + threadIdx.x; i < total8; i += (long)gridDim.x*256){
    int r = (int)(i / cols8);
    int k = (int)(i - (long)r*cols8) * 8;
    short8 v = (k < 512 || !s1) ? cvt8(s0 + (long)r*ld0 + off0 + k)
                                : cvt8(s1 + (long)r*ld1 + off1 + (k-512));
    *(short8*)(dst + (long)r*dld + k) = v;
  }
}

__global__ void bias_sum_kernel(const float* a1, const float* a2, float* o1,
                                const float* b1, const float* b2, float* o2){
  int n = blockIdx.x*256 + threadIdx.x;
  if (n < G_){ o1[n] = a1[n] + a2[n]; o2[n] = b1[n] + b2[n]; }
}

// ---------------------------------------------------------------------------
// mm_pre: out[s] = A_slice(s) @ Wbf.T + bA + bB    (Wbf: [2048][512] bf16)
// A_slice(s): row b at A + b*a_bstride + s*H_.  M=64, N=2048 (8 tiles), K=512.
// ---------------------------------------------------------------------------
__global__ __launch_bounds__(512,1) void mm_pre_kernel(
    const float* __restrict__ A, int a_bstride,
    const unsigned short* __restrict__ Wbf,
    const float* __restrict__ bA, const float* __restrict__ bB,
    float* __restrict__ out)
{
  const int s = blockIdx.x, n0 = blockIdx.y*256;
  const int t = threadIdx.x, w = t>>6, l = t&63, ln = l&15, lk = l>>4;
  __shared__ short8 smA[64*64];
  __shared__ short8 smB[256*8];

  const float* af32 = A + (long)s*H_;

  f32x4 acc[4][2];
#pragma unroll
  for (int mf=0; mf<4; ++mf)
#pragma unroll
    for (int nf=0; nf<2; ++nf) acc[mf][nf] = (f32x4){0.f,0.f,0.f,0.f};

#pragma unroll
  for (int i=0;i<8;++i){ int e=i*4096+t*8; int m=e>>9, k=e&511;
    smA[m*64 + ((k>>3)^(m&7))] = cvt8(&af32[(long)m*a_bstride + k]); }

  for (int kc=0; kc<8; ++kc){
    __syncthreads();
#pragma unroll
    for (int i=0;i<4;++i){ int e=i*4096+t*8; int n=e>>6, k=e&63;
      smB[n*8 + ((k>>3)^(n&7))] = *(const short8*)(Wbf + (long)(n0+n)*512 + kc*64 + k); }
    __syncthreads();
#pragma unroll
    for (int ks2=0; ks2<2; ++ks2){
#pragma unroll
      for (int nf=0; nf<2; ++nf){
        int n = w*32 + nf*16 + ln;
        short8 bfr = smB[n*8 + ((ks2*4+lk)^(n&7))];
#pragma unroll
        for (int mf=0; mf<4; ++mf){
          int m = mf*16+ln;
          short8 afr = smA[m*64 + (((kc*2+ks2)*4+lk)^(m&7))];
          acc[mf][nf] = __builtin_amdgcn_mfma_f32_16x16x32_bf16(afr, bfr, acc[mf][nf], 0,0,0);
        }
      }
    }
  }
#pragma unroll
  for (int nf=0; nf<2; ++nf){
    int n = n0 + w*32 + nf*16 + ln;
    float bias = bA[n] + bB[n];
#pragma unroll
    for (int mf=0; mf<4; ++mf)
#pragma unroll
      for (int r=0; r<4; ++r){
        int m = mf*16 + lk*4 + r;
        out[(long)s*BG_ + (long)m*G_ + n] = acc[mf][nf][r] + bias;
      }
  }
}

// ---------------------------------------------------------------------------
// fused_chain: 64 persistent blocks. Blocks 0..31 = layer-1, 32..63 = layer-2
// (lagging one step). Weights in VGPRs (bf16, unified W[32]; L2 reloads dec
// set at s==49). c-state in LDS. Hierarchical grid barrier:
//   arrival: own padded flag (release) -> block0 gathers -> release gen ->
//   others poll gen with s_sleep backoff.
// ---------------------------------------------------------------------------
__global__ __launch_bounds__(256,1) void fused_chain_kernel(
    const unsigned short* __restrict__ w1e, const unsigned short* __restrict__ w1d, // [2048][512]
    const unsigned short* __restrict__ w2e, const unsigned short* __restrict__ w2d, // [2048][1024]
    const float* __restrict__ x1,   // [48][64][2048]
    const float* __restrict__ capq, // [47][64][2048]
    const float* __restrict__ bd1s, const float* __restrict__ b2es,
    unsigned short* __restrict__ h1, unsigned short* __restrict__ h2, // [96][64][512]
    unsigned* __restrict__ flags, unsigned* __restrict__ gen)
{
  const int bc = blockIdx.x;
  const int isL2 = (bc >= 32);
  const int cb = bc & 31;
  const int t = threadIdx.x;
  const int wv = t>>6, l = t&63, ln = l&15, lk = l>>4;

  __shared__ short8 smA[64*128];        // 128 KB
  __shared__ float gbuf[4][16][68];
  __shared__ float c_lds[16][68];
  unsigned short* stash = (unsigned short*)&smA[0];

  short8 W[32];                          // 128 VGPRs
  const int col = wv*512 + cb*16 + ln;
  if (isL2){
    const long wrow = (long)col * 1024;
#pragma unroll
    for (int ks=0; ks<32; ++ks) W[ks] = *(const short8*)(w2e + wrow + ks*32 + lk*8);
  } else {
    const long wrow = (long)col * 512;
#pragma unroll
    for (int ks=0; ks<16; ++ks){
      W[ks]    = *(const short8*)(w1e + wrow + ks*32 + lk*8);
      W[16+ks] = *(const short8*)(w1d + wrow + ks*32 + lk*8);
    }
  }
  const float bext = isL2 ? b2es[col] : bd1s[col];

  for (int i=t; i<16*68; i+=256) (&c_lds[0][0])[i] = 0.f;

  for (int s=0; s<96; ++s){
    if (isL2 && s == 49){                // enc->dec weight swap for layer-2
      const long wrow = (long)col * 1024;
#pragma unroll
      for (int ks=0; ks<32; ++ks) W[ks] = *(const short8*)(w2d + wrow + ks*32 + lk*8);
    }
    const int active = isL2 ? (s>=1) : (s<95);
    if (active){
      // ---- stage h into LDS ----
      if (!isL2){
        const unsigned short* hp = h1 + (long)s*BH_;
#pragma unroll
        for (int i=0;i<16;++i){ int e=i*2048+t*8; int m=e>>9, k=e&511;
          smA[m*128 + ((k>>3)^(m&7))] = *(const short8*)(hp + m*512 + k); }
      } else {
        const unsigned short* hpA = h2 + (long)(s-1)*BH_;
        const unsigned short* hpB = h1 + (long)s*BH_;
#pragma unroll
        for (int i=0;i<16;++i){ int e=i*2048+t*8; int m=e>>9, k=e&511;
          smA[m*128 + ((k>>3)^(m&7))]      = *(const short8*)(hpA + m*512 + k);
          smA[m*128 + ((k>>3)^(m&7)) + 64] = *(const short8*)(hpB + m*512 + k);
        }
      }

      // ---- prefetch pre/bias values (independent of LDS) ----
      const int dec = isL2 ? ((s-1)>=48) : (s>=48);
      float prev[4][4];
      if (!isL2){
        if (s < 48){
          const float* pp = x1 + (long)s*BG_ + col;
#pragma unroll
          for (int mf=0;mf<4;++mf)
#pragma unroll
            for (int r=0;r<4;++r) prev[mf][r] = pp[(long)(mf*16+lk*4+r)*G_];
        } else {
#pragma unroll
          for (int mf=0;mf<4;++mf)
#pragma unroll
            for (int r=0;r<4;++r) prev[mf][r] = bext;
        }
      } else {
        int s2 = s-1;
        if (s2 < 48){
#pragma unroll
          for (int mf=0;mf<4;++mf)
#pragma unroll
            for (int r=0;r<4;++r) prev[mf][r] = bext;
        } else {
          const float* pp = capq + (long)(s2-48)*BG_ + col;
#pragma unroll
          for (int mf=0;mf<4;++mf)
#pragma unroll
            for (int r=0;r<4;++r) prev[mf][r] = pp[(long)(mf*16+lk*4+r)*G_];
        }
      }
      __syncthreads();

      f32x4 acc[4];
#pragma unroll
      for (int mf=0;mf<4;++mf) acc[mf] = (f32x4){0.f,0.f,0.f,0.f};

      if (isL2){
#pragma unroll
        for (int ks=0; ks<32; ++ks)
#pragma unroll
          for (int mf=0; mf<4; ++mf){
            int m = mf*16+ln;
            acc[mf] = __builtin_amdgcn_mfma_f32_16x16x32_bf16(
              smA[m*128 + ((ks*4+lk)^(m&7))], W[ks], acc[mf], 0,0,0);
          }
      } else if (!dec){
#pragma unroll
        for (int ks=0; ks<16; ++ks)
#pragma unroll
          for (int mf=0; mf<4; ++mf){
            int m = mf*16+ln;
            acc[mf] = __builtin_amdgcn_mfma_f32_16x16x32_bf16(
              smA[m*128 + ((ks*4+lk)^(m&7))], W[ks], acc[mf], 0,0,0);
          }
      } else {
#pragma unroll
        for (int ks=0; ks<16; ++ks)
#pragma unroll
          for (int mf=0; mf<4; ++mf){
            int m = mf*16+ln;
            acc[mf] = __builtin_amdgcn_mfma_f32_16x16x32_bf16(
              smA[m*128 + ((ks*4+lk)^(m&7))], W[16+ks], acc[mf], 0,0,0);
          }
      }

#pragma unroll
      for (int mf=0;mf<4;++mf)
#pragma unroll
        for (int r=0;r<4;++r) acc[mf][r] += prev[mf][r];

#pragma unroll
      for (int mf=0;mf<4;++mf) *(f32x4*)&gbuf[wv][ln][mf*16+lk*4] = acc[mf];
      __syncthreads();

      {
        int n = t&15, m0 = (t>>4)*4;
        float4 gi = *(float4*)&gbuf[0][n][m0];
        float4 gf = *(float4*)&gbuf[1][n][m0];
        float4 gg = *(float4*)&gbuf[2][n][m0];
        float4 go = *(float4*)&gbuf[3][n][m0];
        float4 c4 = *(float4*)&c_lds[n][m0];
        float a_i[4]={gi.x,gi.y,gi.z,gi.w}, a_f[4]={gf.x,gf.y,gf.z,gf.w};
        float a_g[4]={gg.x,gg.y,gg.z,gg.w}, a_o[4]={go.x,go.y,go.z,go.w};
        float ci[4]={c4.x,c4.y,c4.z,c4.w};
        float cn[4];
#pragma unroll
        for (int j=0;j<4;++j){
          float i_ = sigmoidf_(a_i[j]), f_ = sigmoidf_(a_f[j]), o_ = sigmoidf_(a_o[j]);
          float g_ = tanhf(a_g[j]);
          cn[j] = f_*ci[j] + i_*g_;
          stash[(m0+j)*24 + n] = f2bf(o_*tanhf(cn[j]));
        }
        *(float4*)&c_lds[n][m0] = make_float4(cn[0],cn[1],cn[2],cn[3]);
      }
      __syncthreads();

      {
        unsigned short* ho = (isL2 ? (h2 + (long)s*BH_) : (h1 + (long)(s+1)*BH_)) + cb*16;
        if (t < 128){
          int m = t>>1, part = t&1;
          *(short8*)(ho + (long)m*512 + part*8) = *(const short8*)&stash[m*24 + part*8];
        }
      }
    }

    // ---- hierarchical grid barrier (64 blocks) ----
    if (s < 95){
      unsigned g = (unsigned)(s+1);
      __syncthreads();
      if (t == 0){
        __threadfence();
        __hip_atomic_store(&flags[bc*16], g, __ATOMIC_RELEASE, __HIP_MEMORY_SCOPE_AGENT);
      }
      if (bc == 0){
        if (t < 64){
          while (__hip_atomic_load(&flags[t*16], __ATOMIC_ACQUIRE, __HIP_MEMORY_SCOPE_AGENT) < g)
            __builtin_amdgcn_s_sleep(1);
        }
        __syncthreads();
        if (t == 0)
          __hip_atomic_store(gen, g, __ATOMIC_RELEASE, __HIP_MEMORY_SCOPE_AGENT);
      } else {
        if (t == 0){
          while (__hip_atomic_load(gen, __ATOMIC_ACQUIRE, __HIP_MEMORY_SCOPE_AGENT) < g)
            __builtin_amdgcn_s_sleep(2);
          __threadfence();
        }
        __syncthreads();
      }
    }
  }
}

// ---------------------------------------------------------------------------
// CE: logits (bf16 MFMA, pre-converted w_o) + sum-exp partials + target gather
// grid (td 47, vt 125), 512 threads, M=64 N=256 K=512
// ---------------------------------------------------------------------------
__global__ __launch_bounds__(512,1) void ce_mfma_kernel(
    const unsigned short* __restrict__ h2_bf, const unsigned short* __restrict__ wo_bf,
    const float* __restrict__ b_o, const int* __restrict__ ids,
    float* __restrict__ partial, float* __restrict__ tgt)
{
  const int td = blockIdx.x, vt = blockIdx.y, v0 = vt*256;
  const int t = threadIdx.x, w = t>>6, l = t&63, ln = l&15, lk = l>>4;
  __shared__ short8 smA[64*64];
  __shared__ short8 smB[256*8];
  __shared__ float red[8][64];
  __shared__ int tid_s[64];

  const unsigned short* hp = h2_bf + (long)(49+td)*BH_;
  if (t < 64) tid_s[t] = ids[t*T_ + td + 1];
#pragma unroll
  for (int i=0;i<8;++i){ int e=i*4096+t*8; int m=e>>9, k=e&511;
    smA[m*64 + ((k>>3)^(m&7))] = *(const short8*)(hp + m*512 + k); }

  f32x4 acc[4][2];
#pragma unroll
  for (int mf=0; mf<4; ++mf)
#pragma unroll
    for (int nf=0; nf<2; ++nf) acc[mf][nf] = (f32x4){0.f,0.f,0.f,0.f};

  for (int kc=0; kc<8; ++kc){
    __syncthreads();
#pragma unroll
    for (int i=0;i<4;++i){ int e=i*4096+t*8; int n=e>>6, k=e&63;
      smB[n*8 + ((k>>3)^(n&7))] = *(const short8*)(wo_bf + (long)(v0+n)*512 + kc*64 + k); }
    __syncthreads();
#pragma unroll
    for (int ks2=0; ks2<2; ++ks2){
#pragma unroll
      for (int nf=0; nf<2; ++nf){
        int n = w*32 + nf*16 + ln;
        short8 bfr = smB[n*8 + ((ks2*4+lk)^(n&7))];
#pragma unroll
        for (int mf=0; mf<4; ++mf){
          int m = mf*16+ln;
          short8 afr = smA[m*64 + (((kc*2+ks2)*4+lk)^(m&7))];
          acc[mf][nf] = __builtin_amdgcn_mfma_f32_16x16x32_bf16(afr, bfr, acc[mf][nf], 0,0,0);
        }
      }
    }
  }

  float se[4][4];
#pragma unroll
  for (int mf=0; mf<4; ++mf)
#pragma unroll
    for (int r=0;r<4;++r) se[mf][r] = 0.f;
#pragma unroll
  for (int nf=0; nf<2; ++nf){
    int ng = v0 + w*32 + nf*16 + ln;
    float bo = b_o[ng];
#pragma unroll
    for (int mf=0; mf<4; ++mf)
#pragma unroll
      for (int r=0;r<4;++r){
        int m = mf*16 + lk*4 + r;
        float lg = acc[mf][nf][r] + bo;
        se[mf][r] += __expf(lg);
        if (ng == tid_s[m]) tgt[td*64 + m] = lg;
      }
  }
#pragma unroll
  for (int off=1; off<16; off<<=1)
#pragma unroll
    for (int mf=0; mf<4; ++mf)
#pragma unroll
      for (int r=0;r<4;++r) se[mf][r] += __shfl_xor(se[mf][r], off);
  if (ln == 0){
#pragma unroll
    for (int mf=0; mf<4; ++mf)
      *(f32x4*)&red[w][mf*16 + lk*4] = (f32x4){se[mf][0],se[mf][1],se[mf][2],se[mf][3]};
  }
  __syncthreads();
  if (t < 64){
    float ssum = 0.f;
#pragma unroll
    for (int w2=0; w2<8; ++w2) ssum += red[w2][t];
    partial[(long)vt*3008 + td*64 + t] = ssum;
  }
}

__global__ void ce_combine(const float* __restrict__ partial, const float* __restrict__ tgt,
                           float* __restrict__ ce_row){
  int r = blockIdx.x*256 + threadIdx.x;
  if (r < 3008){
    float s = 0.f;
    for (int i=0;i<125;++i) s += partial[(long)i*3008 + r];
    ce_row[r] = __logf(s) - tgt[r];
  }
}

__global__ void ce_final(const float* __restrict__ ce_row, float* __restrict__ out){
  __shared__ float red[256];
  float s = 0.f;
  for (int i=threadIdx.x; i<3008; i+=256) s += ce_row[i];
  red[threadIdx.x] = s;
  __syncthreads();
  for (int off=128; off>0; off>>=1){
    if (threadIdx.x < off) red[threadIdx.x] += red[threadIdx.x + off];
    __syncthreads();
  }
  if (threadIdx.x == 0) out[0] = red[0] * (1.0f/4096.0f);
}

// ---------------------------------------------------------------------------
extern "C" void kernel_launch(void* const* d_in, const int* in_sizes, int n_in,
                              void* d_out, int out_size, void* d_ws, size_t ws_size,
                              hipStream_t stream)
{
  (void)in_sizes; (void)n_in; (void)out_size; (void)ws_size;
  const float* feat    = (const float*)d_in[0];
  const float* caption = (const float*)d_in[1];
  const int*   ids     = (const int*)d_in[2];
  const float* w_ih1  = (const float*)d_in[3];
  const float* w_hh1  = (const float*)d_in[4];
  const float* b_ih1  = (const float*)d_in[5];
  const float* b_hh1  = (const float*)d_in[6];
  const float* w_ih2  = (const float*)d_in[7];
  const float* w_hh2  = (const float*)d_in[8];
  const float* b_ih2  = (const float*)d_in[9];
  const float* b_hh2  = (const float*)d_in[10];
  const float* w_hhd1 = (const float*)d_in[12];
  const float* b_ihd1 = (const float*)d_in[13];
  const float* b_hhd1 = (const float*)d_in[14];
  const float* w_ihd2 = (const float*)d_in[15];
  const float* w_hhd2 = (const float*)d_in[16];
  const float* b_ihd2 = (const float*)d_in[17];
  const float* b_hhd2 = (const float*)d_in[18];
  const float* w_o    = (const float*)d_in[19];
  const float* b_o    = (const float*)d_in[20];

  char* p = (char*)d_ws;
  unsigned short* h1   = (unsigned short*)p; p += 96L*BH_*2;
  unsigned short* h2   = (unsigned short*)p; p += 96L*BH_*2;
  unsigned short* w1e  = (unsigned short*)p; p += 2048L*512*2;
  unsigned short* w1d  = (unsigned short*)p; p += 2048L*512*2;
  unsigned short* w2e  = (unsigned short*)p; p += 2048L*1024*2;
  unsigned short* w2d  = (unsigned short*)p; p += 2048L*1024*2;
  unsigned short* wx1  = (unsigned short*)p; p += 2048L*512*2;
  unsigned short* wcap = (unsigned short*)p; p += 2048L*512*2;
  float* x1    = (float*)p;                                   // 48*BG*4 = 25.2 MB
  unsigned short* wo_bf = (unsigned short*)p;                 // 32000*512*2 = 32.8 MB (aliases x1+capq)
  p += 48L*BG_*4;
  float* capq  = (float*)p; p += 47L*BG_*4;                   // 24.6 MB
  float* bd1s  = (float*)p; p += 2048*4;
  float* b2es  = (float*)p; p += 2048*4;
  float* partial = (float*)p; p += 125L*3008*4;
  float* tgt   = (float*)p; p += 3008*4;
  float* ce_row= (float*)p; p += 3008*4;
  unsigned* flags = (unsigned*)p; p += 1152*4;                // 64 padded flags + gen
  unsigned* gen = flags + 1024;

  init_kernel<<<32, 256, 0, stream>>>(h1, h2, flags);

  // weight conversions to bf16
  cvt_cat_kernel<<<256, 256, 0, stream>>>(w_hh1, 512, 0, nullptr, 0, 0, w1e, 512, 2048L*64);
  cvt_cat_kernel<<<256, 256, 0, stream>>>(w_hhd1, 512, 0, nullptr, 0, 0, w1d, 512, 2048L*64);
  cvt_cat_kernel<<<256, 256, 0, stream>>>(w_hh2, 512, 0, w_ih2, 1024, 512, w2e, 1024, 2048L*128);
  cvt_cat_kernel<<<256, 256, 0, stream>>>(w_hhd2, 512, 0, w_ihd2, 1024, 512, w2d, 1024, 2048L*128);
  cvt_cat_kernel<<<256, 256, 0, stream>>>(w_ih1, 512, 0, nullptr, 0, 0, wx1, 512, 2048L*64);
  cvt_cat_kernel<<<256, 256, 0, stream>>>(w_ihd2, 1024, 0, nullptr, 0, 0, wcap, 512, 2048L*64);
  bias_sum_kernel<<<8, 256, 0, stream>>>(b_ihd1, b_hhd1, bd1s, b_ih2, b_hh2, b2es);

  // X1[s] = feat_s @ w_ih1^T + b_ih1+b_hh1 ;  capQ[j] = cap_j @ w_ihd2[:,:512]^T + b_ihd2+b_hhd2
  mm_pre_kernel<<<dim3(48,8), 512, 0, stream>>>(feat, T_*H_, wx1, b_ih1, b_hh1, x1);
  mm_pre_kernel<<<dim3(47,8), 512, 0, stream>>>(caption, T_*H_, wcap, b_ihd2, b_hhd2, capq);

  // fused two-layer chain, 95 hierarchical grid barriers
  fused_chain_kernel<<<64, 256, 0, stream>>>(w1e, w1d, w2e, w2d, x1, capq, bd1s, b2es, h1, h2, flags, gen);

  // w_o -> bf16 (reuses x1/capq space, safe after chain)
  cvt_cat_kernel<<<512, 256, 0, stream>>>(w_o, 512, 0, nullptr, 0, 0, wo_bf, 512, 32000L*64);

  // CE
  ce_mfma_kernel<<<dim3(47,125), 512, 0, stream>>>(h2, wo_bf, b_o, ids, partial, tgt);
  ce_combine<<<12, 256, 0, stream>>>(partial, tgt, ce_row);
  ce_final<<<1, 256, 0, stream>>>(ce_row, (float*)d_out);
}

// Round 5
// 1479.362 us; speedup vs baseline: 1.5695x; 1.2861x over previous
//
#include <hip/hip_runtime.h>
#include <math.h>

#define B_ 64
#define T_ 48
#define H_ 512
#define V_ 32000
#define G_ 2048
#define BH_ (B_*H_)
#define BG_ (B_*G_)

typedef short short8 __attribute__((ext_vector_type(8)));
typedef float f32x4 __attribute__((ext_vector_type(4)));

__device__ __forceinline__ float sigmoidf_(float x){ return 1.f/(1.f+__expf(-x)); }

__device__ __forceinline__ unsigned short f2bf(float f){
  unsigned u = __float_as_uint(f);
  u += 0x7fffu + ((u>>16)&1u);
  return (unsigned short)(u>>16);
}

__device__ __forceinline__ short8 cvt8(const float* g){
  float4 a = *(const float4*)g;
  float4 b = *(const float4*)(g+4);
  short8 v;
  v[0]=(short)f2bf(a.x); v[1]=(short)f2bf(a.y); v[2]=(short)f2bf(a.z); v[3]=(short)f2bf(a.w);
  v[4]=(short)f2bf(b.x); v[5]=(short)f2bf(b.y); v[6]=(short)f2bf(b.z); v[7]=(short)f2bf(b.w);
  return v;
}

// ---------------------------------------------------------------------------
// init: zero h1[0], h2[0] (bf16) and the grid-barrier flags
// ---------------------------------------------------------------------------
__global__ void init_kernel(unsigned short* h1_0, unsigned short* h2_0, unsigned* flags){
  int i = blockIdx.x*256 + threadIdx.x;   // 32 blocks -> 8192 threads
  short8 z = {0,0,0,0,0,0,0,0};
  if (i < 4096) ((short8*)h1_0)[i] = z;
  else          ((short8*)h2_0)[i-4096] = z;
  if (i < 1152) flags[i] = 0u;
}

// ---------------------------------------------------------------------------
// cvt_cat: dst[r][0..511] = bf16(s0[r*ld0+off0+k]); dst[r][512..dld) from s1
// ---------------------------------------------------------------------------
__global__ void cvt_cat_kernel(const float* __restrict__ s0, int ld0, int off0,
                               const float* __restrict__ s1, int ld1, int off1,
                               unsigned short* __restrict__ dst, int dld, long total8)
{
  int cols8 = dld >> 3;
  for (long i = blockIdx.x*256 + threadIdx.x; i < total8; i += (long)gridDim.x*256){
    int r = (int)(i / cols8);
    int k = (int)(i - (long)r*cols8) * 8;
    short8 v = (k < 512 || !s1) ? cvt8(s0 + (long)r*ld0 + off0 + k)
                                : cvt8(s1 + (long)r*ld1 + off1 + (k-512));
    *(short8*)(dst + (long)r*dld + k) = v;
  }
}

__global__ void bias_sum_kernel(const float* a1, const float* a2, float* o1,
                                const float* b1, const float* b2, float* o2){
  int n = blockIdx.x*256 + threadIdx.x;
  if (n < G_){ o1[n] = a1[n] + a2[n]; o2[n] = b1[n] + b2[n]; }
}

// ---------------------------------------------------------------------------
// mm_pre: out[s] = A_slice(s) @ Wbf.T + bA + bB    (Wbf: [2048][512] bf16)
// ---------------------------------------------------------------------------
__global__ __launch_bounds__(512,1) void mm_pre_kernel(
    const float* __restrict__ A, int a_bstride,
    const unsigned short* __restrict__ Wbf,
    const float* __restrict__ bA, const float* __restrict__ bB,
    float* __restrict__ out)
{
  const int s = blockIdx.x, n0 = blockIdx.y*256;
  const int t = threadIdx.x, w = t>>6, l = t&63, ln = l&15, lk = l>>4;
  __shared__ short8 smA[64*64];
  __shared__ short8 smB[256*8];

  const float* af32 = A + (long)s*H_;

  f32x4 acc[4][2];
#pragma unroll
  for (int mf=0; mf<4; ++mf)
#pragma unroll
    for (int nf=0; nf<2; ++nf) acc[mf][nf] = (f32x4){0.f,0.f,0.f,0.f};

#pragma unroll
  for (int i=0;i<8;++i){ int e=i*4096+t*8; int m=e>>9, k=e&511;
    smA[m*64 + ((k>>3)^(m&7))] = cvt8(&af32[(long)m*a_bstride + k]); }

  for (int kc=0; kc<8; ++kc){
    __syncthreads();
#pragma unroll
    for (int i=0;i<4;++i){ int e=i*4096+t*8; int n=e>>6, k=e&63;
      smB[n*8 + ((k>>3)^(n&7))] = *(const short8*)(Wbf + (long)(n0+n)*512 + kc*64 + k); }
    __syncthreads();
#pragma unroll
    for (int ks2=0; ks2<2; ++ks2){
#pragma unroll
      for (int nf=0; nf<2; ++nf){
        int n = w*32 + nf*16 + ln;
        short8 bfr = smB[n*8 + ((ks2*4+lk)^(n&7))];
#pragma unroll
        for (int mf=0; mf<4; ++mf){
          int m = mf*16+ln;
          short8 afr = smA[m*64 + (((kc*2+ks2)*4+lk)^(m&7))];
          acc[mf][nf] = __builtin_amdgcn_mfma_f32_16x16x32_bf16(afr, bfr, acc[mf][nf], 0,0,0);
        }
      }
    }
  }
#pragma unroll
  for (int nf=0; nf<2; ++nf){
    int n = n0 + w*32 + nf*16 + ln;
    float bias = bA[n] + bB[n];
#pragma unroll
    for (int mf=0; mf<4; ++mf)
#pragma unroll
      for (int r=0; r<4; ++r){
        int m = mf*16 + lk*4 + r;
        out[(long)s*BG_ + (long)m*G_ + n] = acc[mf][nf][r] + bias;
      }
  }
}

// ---------------------------------------------------------------------------
// fused_chain: 64 persistent blocks. Blocks 0..31 = layer-1, 32..63 = layer-2
// (lagging one step). Weights in VGPRs. c-state in LDS.
// h exchange: agent-coherent relaxed atomic u64 stores (write-through to IF$,
// no wbl2/inv cache ops anywhere). Flags: relaxed agent atomics; consumer
// data loads stay plain (each h address read only after its barrier, never
// re-read -> no stale-line hazard within a launch).
// ---------------------------------------------------------------------------
__global__ __launch_bounds__(256,1) void fused_chain_kernel(
    const unsigned short* __restrict__ w1e, const unsigned short* __restrict__ w1d, // [2048][512]
    const unsigned short* __restrict__ w2e, const unsigned short* __restrict__ w2d, // [2048][1024]
    const float* __restrict__ x1,   // [48][64][2048]
    const float* __restrict__ capq, // [47][64][2048]
    const float* __restrict__ bd1s, const float* __restrict__ b2es,
    unsigned short* __restrict__ h1, unsigned short* __restrict__ h2, // [96][64][512]
    unsigned* __restrict__ flags)
{
  const int bc = blockIdx.x;
  const int isL2 = (bc >= 32);
  const int cb = bc & 31;
  const int t = threadIdx.x;
  const int wv = t>>6, l = t&63, ln = l&15, lk = l>>4;

  __shared__ short8 smA[64*128];        // 128 KB
  __shared__ float gbuf[4][16][68];
  __shared__ float c_lds[16][68];
  unsigned short* stash = (unsigned short*)&smA[0];

  short8 W[32];                          // 128 VGPRs
  const int col = wv*512 + cb*16 + ln;
  if (isL2){
    const long wrow = (long)col * 1024;
#pragma unroll
    for (int ks=0; ks<32; ++ks) W[ks] = *(const short8*)(w2e + wrow + ks*32 + lk*8);
  } else {
    const long wrow = (long)col * 512;
#pragma unroll
    for (int ks=0; ks<16; ++ks){
      W[ks]    = *(const short8*)(w1e + wrow + ks*32 + lk*8);
      W[16+ks] = *(const short8*)(w1d + wrow + ks*32 + lk*8);
    }
  }
  const float bext = isL2 ? b2es[col] : bd1s[col];

  for (int i=t; i<16*68; i+=256) (&c_lds[0][0])[i] = 0.f;

  for (int s=0; s<96; ++s){
    if (isL2 && s == 49){                // enc->dec weight swap for layer-2
      const long wrow = (long)col * 1024;
#pragma unroll
      for (int ks=0; ks<32; ++ks) W[ks] = *(const short8*)(w2d + wrow + ks*32 + lk*8);
    }
    const int active = isL2 ? (s>=1) : (s<95);
    if (active){
      // ---- stage h into LDS (plain cached loads — see header comment) ----
      if (!isL2){
        const unsigned short* hp = h1 + (long)s*BH_;
#pragma unroll
        for (int i=0;i<16;++i){ int e=i*2048+t*8; int m=e>>9, k=e&511;
          smA[m*128 + ((k>>3)^(m&7))] = *(const short8*)(hp + m*512 + k); }
      } else {
        const unsigned short* hpA = h2 + (long)(s-1)*BH_;
        const unsigned short* hpB = h1 + (long)s*BH_;
#pragma unroll
        for (int i=0;i<16;++i){ int e=i*2048+t*8; int m=e>>9, k=e&511;
          smA[m*128 + ((k>>3)^(m&7))]      = *(const short8*)(hpA + m*512 + k);
          smA[m*128 + ((k>>3)^(m&7)) + 64] = *(const short8*)(hpB + m*512 + k);
        }
      }

      // ---- prefetch pre/bias values ----
      const int dec = isL2 ? ((s-1)>=48) : (s>=48);
      float prev[4][4];
      if (!isL2){
        if (s < 48){
          const float* pp = x1 + (long)s*BG_ + col;
#pragma unroll
          for (int mf=0;mf<4;++mf)
#pragma unroll
            for (int r=0;r<4;++r) prev[mf][r] = pp[(long)(mf*16+lk*4+r)*G_];
        } else {
#pragma unroll
          for (int mf=0;mf<4;++mf)
#pragma unroll
            for (int r=0;r<4;++r) prev[mf][r] = bext;
        }
      } else {
        int s2 = s-1;
        if (s2 < 48){
#pragma unroll
          for (int mf=0;mf<4;++mf)
#pragma unroll
            for (int r=0;r<4;++r) prev[mf][r] = bext;
        } else {
          const float* pp = capq + (long)(s2-48)*BG_ + col;
#pragma unroll
          for (int mf=0;mf<4;++mf)
#pragma unroll
            for (int r=0;r<4;++r) prev[mf][r] = pp[(long)(mf*16+lk*4+r)*G_];
        }
      }
      __syncthreads();

      f32x4 acc[4];
#pragma unroll
      for (int mf=0;mf<4;++mf) acc[mf] = (f32x4){0.f,0.f,0.f,0.f};

      if (isL2){
#pragma unroll
        for (int ks=0; ks<32; ++ks)
#pragma unroll
          for (int mf=0; mf<4; ++mf){
            int m = mf*16+ln;
            acc[mf] = __builtin_amdgcn_mfma_f32_16x16x32_bf16(
              smA[m*128 + ((ks*4+lk)^(m&7))], W[ks], acc[mf], 0,0,0);
          }
      } else if (!dec){
#pragma unroll
        for (int ks=0; ks<16; ++ks)
#pragma unroll
          for (int mf=0; mf<4; ++mf){
            int m = mf*16+ln;
            acc[mf] = __builtin_amdgcn_mfma_f32_16x16x32_bf16(
              smA[m*128 + ((ks*4+lk)^(m&7))], W[ks], acc[mf], 0,0,0);
          }
      } else {
#pragma unroll
        for (int ks=0; ks<16; ++ks)
#pragma unroll
          for (int mf=0; mf<4; ++mf){
            int m = mf*16+ln;
            acc[mf] = __builtin_amdgcn_mfma_f32_16x16x32_bf16(
              smA[m*128 + ((ks*4+lk)^(m&7))], W[16+ks], acc[mf], 0,0,0);
          }
      }

#pragma unroll
      for (int mf=0;mf<4;++mf)
#pragma unroll
        for (int r=0;r<4;++r) acc[mf][r] += prev[mf][r];

#pragma unroll
      for (int mf=0;mf<4;++mf) *(f32x4*)&gbuf[wv][ln][mf*16+lk*4] = acc[mf];
      __syncthreads();

      {
        int n = t&15, m0 = (t>>4)*4;
        float4 gi = *(float4*)&gbuf[0][n][m0];
        float4 gf = *(float4*)&gbuf[1][n][m0];
        float4 gg = *(float4*)&gbuf[2][n][m0];
        float4 go = *(float4*)&gbuf[3][n][m0];
        float4 c4 = *(float4*)&c_lds[n][m0];
        float a_i[4]={gi.x,gi.y,gi.z,gi.w}, a_f[4]={gf.x,gf.y,gf.z,gf.w};
        float a_g[4]={gg.x,gg.y,gg.z,gg.w}, a_o[4]={go.x,go.y,go.z,go.w};
        float ci[4]={c4.x,c4.y,c4.z,c4.w};
        float cn[4];
#pragma unroll
        for (int j=0;j<4;++j){
          float i_ = sigmoidf_(a_i[j]), f_ = sigmoidf_(a_f[j]), o_ = sigmoidf_(a_o[j]);
          float g_ = tanhf(a_g[j]);
          cn[j] = f_*ci[j] + i_*g_;
          stash[(m0+j)*24 + n] = f2bf(o_*tanhf(cn[j]));
        }
        *(float4*)&c_lds[n][m0] = make_float4(cn[0],cn[1],cn[2],cn[3]);
      }
      __syncthreads();

      {
        // agent-coherent write-through store of this block's 16 h-cols
        unsigned short* ho = (isL2 ? (h2 + (long)s*BH_) : (h1 + (long)(s+1)*BH_)) + cb*16;
        int m = t>>2, q = t&3;
        unsigned long long v = *(const unsigned long long*)&stash[m*24 + q*4];
        __hip_atomic_store((unsigned long long*)(ho + (long)m*512 + q*4), v,
                           __ATOMIC_RELAXED, __HIP_MEMORY_SCOPE_AGENT);
      }
    }

    // ---- all-to-all flag barrier: no fences, no RMW, no cache maintenance --
    if (s < 95){
      unsigned g = (unsigned)(s+1);
      __syncthreads();   // compiler drains vmcnt(0) per wave before s_barrier
      if (t == 0)
        __hip_atomic_store(&flags[bc*16], g, __ATOMIC_RELAXED, __HIP_MEMORY_SCOPE_AGENT);
      if (t < 64){
        while (__hip_atomic_load(&flags[t*16], __ATOMIC_RELAXED, __HIP_MEMORY_SCOPE_AGENT) < g)
          __builtin_amdgcn_s_sleep(1);
      }
      __syncthreads();
    }
  }
}

// ---------------------------------------------------------------------------
// CE: logits (bf16 MFMA, pre-converted w_o) + sum-exp partials + target gather
// ---------------------------------------------------------------------------
__global__ __launch_bounds__(512,1) void ce_mfma_kernel(
    const unsigned short* __restrict__ h2_bf, const unsigned short* __restrict__ wo_bf,
    const float* __restrict__ b_o, const int* __restrict__ ids,
    float* __restrict__ partial, float* __restrict__ tgt)
{
  const int td = blockIdx.x, vt = blockIdx.y, v0 = vt*256;
  const int t = threadIdx.x, w = t>>6, l = t&63, ln = l&15, lk = l>>4;
  __shared__ short8 smA[64*64];
  __shared__ short8 smB[256*8];
  __shared__ float red[8][64];
  __shared__ int tid_s[64];

  const unsigned short* hp = h2_bf + (long)(49+td)*BH_;
  if (t < 64) tid_s[t] = ids[t*T_ + td + 1];
#pragma unroll
  for (int i=0;i<8;++i){ int e=i*4096+t*8; int m=e>>9, k=e&511;
    smA[m*64 + ((k>>3)^(m&7))] = *(const short8*)(hp + m*512 + k); }

  f32x4 acc[4][2];
#pragma unroll
  for (int mf=0; mf<4; ++mf)
#pragma unroll
    for (int nf=0; nf<2; ++nf) acc[mf][nf] = (f32x4){0.f,0.f,0.f,0.f};

  for (int kc=0; kc<8; ++kc){
    __syncthreads();
#pragma unroll
    for (int i=0;i<4;++i){ int e=i*4096+t*8; int n=e>>6, k=e&63;
      smB[n*8 + ((k>>3)^(n&7))] = *(const short8*)(wo_bf + (long)(v0+n)*512 + kc*64 + k); }
    __syncthreads();
#pragma unroll
    for (int ks2=0; ks2<2; ++ks2){
#pragma unroll
      for (int nf=0; nf<2; ++nf){
        int n = w*32 + nf*16 + ln;
        short8 bfr = smB[n*8 + ((ks2*4+lk)^(n&7))];
#pragma unroll
        for (int mf=0; mf<4; ++mf){
          int m = mf*16+ln;
          short8 afr = smA[m*64 + (((kc*2+ks2)*4+lk)^(m&7))];
          acc[mf][nf] = __builtin_amdgcn_mfma_f32_16x16x32_bf16(afr, bfr, acc[mf][nf], 0,0,0);
        }
      }
    }
  }

  float se[4][4];
#pragma unroll
  for (int mf=0; mf<4; ++mf)
#pragma unroll
    for (int r=0;r<4;++r) se[mf][r] = 0.f;
#pragma unroll
  for (int nf=0; nf<2; ++nf){
    int ng = v0 + w*32 + nf*16 + ln;
    float bo = b_o[ng];
#pragma unroll
    for (int mf=0; mf<4; ++mf)
#pragma unroll
      for (int r=0;r<4;++r){
        int m = mf*16 + lk*4 + r;
        float lg = acc[mf][nf][r] + bo;
        se[mf][r] += __expf(lg);
        if (ng == tid_s[m]) tgt[td*64 + m] = lg;
      }
  }
#pragma unroll
  for (int off=1; off<16; off<<=1)
#pragma unroll
    for (int mf=0; mf<4; ++mf)
#pragma unroll
      for (int r=0;r<4;++r) se[mf][r] += __shfl_xor(se[mf][r], off);
  if (ln == 0){
#pragma unroll
    for (int mf=0; mf<4; ++mf)
      *(f32x4*)&red[w][mf*16 + lk*4] = (f32x4){se[mf][0],se[mf][1],se[mf][2],se[mf][3]};
  }
  __syncthreads();
  if (t < 64){
    float ssum = 0.f;
#pragma unroll
    for (int w2=0; w2<8; ++w2) ssum += red[w2][t];
    partial[(long)vt*3008 + td*64 + t] = ssum;
  }
}

__global__ void ce_combine(const float* __restrict__ partial, const float* __restrict__ tgt,
                           float* __restrict__ ce_row){
  int r = blockIdx.x*256 + threadIdx.x;
  if (r < 3008){
    float s = 0.f;
    for (int i=0;i<125;++i) s += partial[(long)i*3008 + r];
    ce_row[r] = __logf(s) - tgt[r];
  }
}

__global__ void ce_final(const float* __restrict__ ce_row, float* __restrict__ out){
  __shared__ float red[256];
  float s = 0.f;
  for (int i=threadIdx.x; i<3008; i+=256) s += ce_row[i];
  red[threadIdx.x] = s;
  __syncthreads();
  for (int off=128; off>0; off>>=1){
    if (threadIdx.x < off) red[threadIdx.x] += red[threadIdx.x + off];
    __syncthreads();
  }
  if (threadIdx.x == 0) out[0] = red[0] * (1.0f/4096.0f);
}

// ---------------------------------------------------------------------------
extern "C" void kernel_launch(void* const* d_in, const int* in_sizes, int n_in,
                              void* d_out, int out_size, void* d_ws, size_t ws_size,
                              hipStream_t stream)
{
  (void)in_sizes; (void)n_in; (void)out_size; (void)ws_size;
  const float* feat    = (const float*)d_in[0];
  const float* caption = (const float*)d_in[1];
  const int*   ids     = (const int*)d_in[2];
  const float* w_ih1  = (const float*)d_in[3];
  const float* w_hh1  = (const float*)d_in[4];
  const float* b_ih1  = (const float*)d_in[5];
  const float* b_hh1  = (const float*)d_in[6];
  const float* w_ih2  = (const float*)d_in[7];
  const float* w_hh2  = (const float*)d_in[8];
  const float* b_ih2  = (const float*)d_in[9];
  const float* b_hh2  = (const float*)d_in[10];
  const float* w_hhd1 = (const float*)d_in[12];
  const float* b_ihd1 = (const float*)d_in[13];
  const float* b_hhd1 = (const float*)d_in[14];
  const float* w_ihd2 = (const float*)d_in[15];
  const float* w_hhd2 = (const float*)d_in[16];
  const float* b_ihd2 = (const float*)d_in[17];
  const float* b_hhd2 = (const float*)d_in[18];
  const float* w_o    = (const float*)d_in[19];
  const float* b_o    = (const float*)d_in[20];

  char* p = (char*)d_ws;
  unsigned short* h1   = (unsigned short*)p; p += 96L*BH_*2;
  unsigned short* h2   = (unsigned short*)p; p += 96L*BH_*2;
  unsigned short* w1e  = (unsigned short*)p; p += 2048L*512*2;
  unsigned short* w1d  = (unsigned short*)p; p += 2048L*512*2;
  unsigned short* w2e  = (unsigned short*)p; p += 2048L*1024*2;
  unsigned short* w2d  = (unsigned short*)p; p += 2048L*1024*2;
  unsigned short* wx1  = (unsigned short*)p; p += 2048L*512*2;
  unsigned short* wcap = (unsigned short*)p; p += 2048L*512*2;
  float* x1    = (float*)p;                                   // 48*BG*4 = 25.2 MB
  unsigned short* wo_bf = (unsigned short*)p;                 // 32.8 MB (aliases x1+capq)
  p += 48L*BG_*4;
  float* capq  = (float*)p; p += 47L*BG_*4;                   // 24.6 MB
  float* bd1s  = (float*)p; p += 2048*4;
  float* b2es  = (float*)p; p += 2048*4;
  float* partial = (float*)p; p += 125L*3008*4;
  float* tgt   = (float*)p; p += 3008*4;
  float* ce_row= (float*)p; p += 3008*4;
  unsigned* flags = (unsigned*)p; p += 1152*4;                // 64 padded flags

  init_kernel<<<32, 256, 0, stream>>>(h1, h2, flags);

  // weight conversions to bf16
  cvt_cat_kernel<<<256, 256, 0, stream>>>(w_hh1, 512, 0, nullptr, 0, 0, w1e, 512, 2048L*64);
  cvt_cat_kernel<<<256, 256, 0, stream>>>(w_hhd1, 512, 0, nullptr, 0, 0, w1d, 512, 2048L*64);
  cvt_cat_kernel<<<256, 256, 0, stream>>>(w_hh2, 512, 0, w_ih2, 1024, 512, w2e, 1024, 2048L*128);
  cvt_cat_kernel<<<256, 256, 0, stream>>>(w_hhd2, 512, 0, w_ihd2, 1024, 512, w2d, 1024, 2048L*128);
  cvt_cat_kernel<<<256, 256, 0, stream>>>(w_ih1, 512, 0, nullptr, 0, 0, wx1, 512, 2048L*64);
  cvt_cat_kernel<<<256, 256, 0, stream>>>(w_ihd2, 1024, 0, nullptr, 0, 0, wcap, 512, 2048L*64);
  bias_sum_kernel<<<8, 256, 0, stream>>>(b_ihd1, b_hhd1, bd1s, b_ih2, b_hh2, b2es);

  // X1[s] = feat_s @ w_ih1^T + b_ih1+b_hh1 ;  capQ[j] = cap_j @ w_ihd2[:,:512]^T + b_ihd2+b_hhd2
  mm_pre_kernel<<<dim3(48,8), 512, 0, stream>>>(feat, T_*H_, wx1, b_ih1, b_hh1, x1);
  mm_pre_kernel<<<dim3(47,8), 512, 0, stream>>>(caption, T_*H_, wcap, b_ihd2, b_hhd2, capq);

  // fused two-layer chain, 95 lightweight grid barriers
  fused_chain_kernel<<<64, 256, 0, stream>>>(w1e, w1d, w2e, w2d, x1, capq, bd1s, b2es, h1, h2, flags);

  // w_o -> bf16 (reuses x1/capq space, safe after chain)
  cvt_cat_kernel<<<512, 256, 0, stream>>>(w_o, 512, 0, nullptr, 0, 0, wo_bf, 512, 32000L*64);

  // CE
  ce_mfma_kernel<<<dim3(47,125), 512, 0, stream>>>(h2, wo_bf, b_o, ids, partial, tgt);
  ce_combine<<<12, 256, 0, stream>>>(partial, tgt, ce_row);
  ce_final<<<1, 256, 0, stream>>>(ce_row, (float*)d_out);
}